// Round 1
// baseline (585.242 us; speedup 1.0000x reference)
//
#include <hip/hip_runtime.h>

typedef __attribute__((ext_vector_type(8))) short s16x8;
typedef __attribute__((ext_vector_type(4))) float f32x4;

#define T_  2048
#define C_  1024
#define D_  64

__device__ __forceinline__ unsigned short f2bf(float f){
  union { float fv; unsigned int u; } v; v.fv = f;
  unsigned int r = v.u + 0x7FFFu + ((v.u >> 16) & 1u);
  return (unsigned short)(r >> 16);
}

__device__ __forceinline__ void gload_lds16(const void* g, void* l){
  __builtin_amdgcn_global_load_lds(
      (const __attribute__((address_space(1))) unsigned int*)g,
      (__attribute__((address_space(3))) unsigned int*)l, 16, 0, 0);
}

// ---------------- fp32 -> bf16 convert, 8 elems/thread ----------------
__global__ __launch_bounds__(256) void cvt_kernel(const float* __restrict__ src,
                                                  unsigned short* __restrict__ dst){
  size_t i = ((size_t)blockIdx.x * 256u + threadIdx.x) * 8u;
  f32x4 a = *(const f32x4*)(src + i);
  f32x4 b = *(const f32x4*)(src + i + 4);
  s16x8 o;
  #pragma unroll
  for (int j = 0; j < 4; ++j){ o[j] = (short)f2bf(a[j]); o[4+j] = (short)f2bf(b[j]); }
  *(s16x8*)(dst + i) = o;
}

// ---------------- GEMM: C[m,n] = sum_k A[m,k]*Bw[n,k] + bias[n] ----------------
// MODE 0: QKV epilogue -> scatter q(scaled)/k/[vT transposed], bf16
// MODE 1: plain fp32 output
template<int MODE>
__global__ __launch_bounds__(256) void gemm_bt(
    const unsigned short* __restrict__ A, const unsigned short* __restrict__ Bw,
    const float* __restrict__ bias, int M, int N, int K,
    unsigned short* __restrict__ q_ws, unsigned short* __restrict__ k_ws,
    unsigned short* __restrict__ vT_ws, float* __restrict__ out)
{
  __shared__ unsigned short As[128*32];
  __shared__ unsigned short Bs[128*32];
  const int tid = threadIdx.x;
  const int lane = tid & 63, wid = tid >> 6;
  const int g = lane >> 4, lr = lane & 15;
  const int m0 = blockIdx.y * 128, n0 = blockIdx.x * 128;
  const int wr = wid >> 1, wc = wid & 1;

  f32x4 acc[4][4];
  #pragma unroll
  for (int i = 0; i < 4; ++i)
    #pragma unroll
    for (int j = 0; j < 4; ++j) acc[i][j] = (f32x4){0.f,0.f,0.f,0.f};

  const int nk = K >> 5;
  for (int kt = 0; kt < nk; ++kt){
    const int k0 = kt << 5;
    #pragma unroll
    for (int j = 0; j < 2; ++j){
      const int c = wid*128 + j*64 + lane;
      const int row = c >> 2, kc = c & 3;
      gload_lds16((const char*)A  + (((size_t)(m0+row))*K + k0)*2 + kc*16,
                  (char*)As + (size_t)(wid*128 + j*64)*16);
      gload_lds16((const char*)Bw + (((size_t)(n0+row))*K + k0)*2 + kc*16,
                  (char*)Bs + (size_t)(wid*128 + j*64)*16);
    }
    __syncthreads();
    s16x8 af[4], bf[4];
    #pragma unroll
    for (int i = 0; i < 4; ++i)
      af[i] = *(const s16x8*)&As[(wr*64 + i*16 + lr)*32 + g*8];
    #pragma unroll
    for (int j = 0; j < 4; ++j)
      bf[j] = *(const s16x8*)&Bs[(wc*64 + j*16 + lr)*32 + g*8];
    #pragma unroll
    for (int i = 0; i < 4; ++i)
      #pragma unroll
      for (int j = 0; j < 4; ++j)
        acc[i][j] = __builtin_amdgcn_mfma_f32_16x16x32_bf16(af[i], bf[j], acc[i][j], 0, 0, 0);
    __syncthreads();
  }

  #pragma unroll
  for (int i = 0; i < 4; ++i){
    #pragma unroll
    for (int j = 0; j < 4; ++j){
      const int n = n0 + wc*64 + j*16 + lr;
      const float bv = bias[n];
      #pragma unroll
      for (int r = 0; r < 4; ++r){
        const int m = m0 + wr*64 + i*16 + g*4 + r;
        const float val = acc[i][j][r] + bv;
        if (MODE == 0){
          const int which = n >> 10;
          const int cc = n & 1023;
          const int h = cc >> 6, d = cc & 63;
          const int bq = m >> 11, t = m & 2047;
          const int bh = bq*16 + h;
          if (which == 0)      q_ws[((size_t)bh*T_ + t)*D_ + d] = f2bf(val * 0.015625f); // 1/head_dim folded into q
          else if (which == 1) k_ws[((size_t)bh*T_ + t)*D_ + d] = f2bf(val);
          else                 vT_ws[((size_t)bh*D_ + d)*T_ + t] = f2bf(val);           // V stored transposed
        } else {
          out[(size_t)m*N + n] = val;
        }
      }
    }
  }
}

// ---------------- flash attention: 4 indep waves/block, 16 q/wave, 32-key tiles ----------------
__global__ __launch_bounds__(256) void attn_kernel(
    const unsigned short* __restrict__ q_ws, const unsigned short* __restrict__ k_ws,
    const unsigned short* __restrict__ vT_ws, unsigned short* __restrict__ y_ws)
{
  __shared__ unsigned short P_lds[4][16*32];
  const int tid = threadIdx.x;
  const int lane = tid & 63, wid = tid >> 6;
  const int g = lane >> 4, lr = lane & 15;
  const int qt = (int)gridDim.x - 1 - (int)blockIdx.x;   // heavy q-tiles dispatch first
  const int bh = blockIdx.y;
  const int qw0 = qt*64 + wid*16;

  const unsigned short* Qb = q_ws  + (size_t)bh*T_*D_;
  const unsigned short* Kb = k_ws  + (size_t)bh*T_*D_;
  const unsigned short* Vb = vT_ws + (size_t)bh*D_*T_;

  const s16x8 aq0 = *(const s16x8*)&Qb[(size_t)(qw0+lr)*D_ + g*8];
  const s16x8 aq1 = *(const s16x8*)&Qb[(size_t)(qw0+lr)*D_ + 32 + g*8];

  f32x4 yacc[4];
  #pragma unroll
  for (int d = 0; d < 4; ++d) yacc[d] = (f32x4){0.f,0.f,0.f,0.f};
  float mrun[4] = {-1e30f,-1e30f,-1e30f,-1e30f};
  float lrun[4] = {0.f,0.f,0.f,0.f};

  const int ktend = qw0 + 15;
  for (int kt0 = 0; kt0 <= ktend; kt0 += 32){
    const s16x8 bk00 = *(const s16x8*)&Kb[(size_t)(kt0 + lr)*D_ + g*8];
    const s16x8 bk01 = *(const s16x8*)&Kb[(size_t)(kt0 + lr)*D_ + 32 + g*8];
    const s16x8 bk10 = *(const s16x8*)&Kb[(size_t)(kt0 + 16 + lr)*D_ + g*8];
    const s16x8 bk11 = *(const s16x8*)&Kb[(size_t)(kt0 + 16 + lr)*D_ + 32 + g*8];
    f32x4 s0 = (f32x4){0.f,0.f,0.f,0.f}, s1 = (f32x4){0.f,0.f,0.f,0.f};
    s0 = __builtin_amdgcn_mfma_f32_16x16x32_bf16(aq0, bk00, s0, 0, 0, 0);
    s0 = __builtin_amdgcn_mfma_f32_16x16x32_bf16(aq1, bk01, s0, 0, 0, 0);
    s1 = __builtin_amdgcn_mfma_f32_16x16x32_bf16(aq0, bk10, s1, 0, 0, 0);
    s1 = __builtin_amdgcn_mfma_f32_16x16x32_bf16(aq1, bk11, s1, 0, 0, 0);

    #pragma unroll
    for (int r = 0; r < 4; ++r){
      const int qrow = qw0 + g*4 + r;
      float v0 = (kt0 + lr      <= qrow) ? s0[r] : -1e30f;   // causal mask
      float v1 = (kt0 + 16 + lr <= qrow) ? s1[r] : -1e30f;
      float mx = fmaxf(v0, v1);
      #pragma unroll
      for (int d = 1; d < 16; d <<= 1) mx = fmaxf(mx, __shfl_xor(mx, d, 64));
      const float mnew = fmaxf(mrun[r], mx);
      const float corr = __expf(mrun[r] - mnew);
      const float p0 = __expf(v0 - mnew);
      const float p1 = __expf(v1 - mnew);
      float rs = p0 + p1;
      #pragma unroll
      for (int d = 1; d < 16; d <<= 1) rs += __shfl_xor(rs, d, 64);
      lrun[r] = lrun[r]*corr + rs;
      mrun[r] = mnew;
      #pragma unroll
      for (int db = 0; db < 4; ++db) yacc[db][r] *= corr;
      P_lds[wid][(g*4+r)*32 + lr]      = f2bf(p0);   // re-fragment P via per-wave LDS
      P_lds[wid][(g*4+r)*32 + 16 + lr] = f2bf(p1);
    }
    asm volatile("" ::: "memory");  // keep compiler from moving the read above the writes
    const s16x8 pa = *(const s16x8*)&P_lds[wid][lr*32 + g*8];
    #pragma unroll
    for (int db = 0; db < 4; ++db){
      const s16x8 bv = *(const s16x8*)&Vb[(size_t)(db*16 + lr)*T_ + kt0 + g*8]; // contiguous: V is transposed
      yacc[db] = __builtin_amdgcn_mfma_f32_16x16x32_bf16(pa, bv, yacc[db], 0, 0, 0);
    }
  }

  const int bq = bh >> 4, h = bh & 15;
  #pragma unroll
  for (int db = 0; db < 4; ++db){
    #pragma unroll
    for (int r = 0; r < 4; ++r){
      const int t = qw0 + g*4 + r;
      const float val = yacc[db][r] / lrun[r];
      y_ws[((size_t)(bq*T_ + t))*C_ + h*64 + db*16 + lr] = f2bf(val);
    }
  }
}

extern "C" void kernel_launch(void* const* d_in, const int* in_sizes, int n_in,
                              void* d_out, int out_size, void* d_ws, size_t ws_size,
                              hipStream_t stream) {
  const float* x  = (const float*)d_in[0];
  const float* Wa = (const float*)d_in[1];
  const float* ba = (const float*)d_in[2];
  const float* Wp = (const float*)d_in[3];
  const float* bp = (const float*)d_in[4];
  float* out = (float*)d_out;

  char* ws = (char*)d_ws;
  const size_t MB = 1024u*1024u;
  unsigned short* xb  = (unsigned short*)(ws + 0);       // 16 MiB  [8192][1024] bf16
  unsigned short* wab = (unsigned short*)(ws + 16*MB);   //  6 MiB  [3072][1024]
  unsigned short* wpb = (unsigned short*)(ws + 22*MB);   //  2 MiB  [1024][1024]
  unsigned short* qws = (unsigned short*)(ws + 24*MB);   // 16 MiB  [64][2048][64]
  unsigned short* kws = (unsigned short*)(ws + 40*MB);   // 16 MiB  [64][2048][64]
  unsigned short* vT  = (unsigned short*)(ws + 56*MB);   // 16 MiB  [64][64][2048]
  unsigned short* yws = (unsigned short*)(ws + 72*MB);   // 16 MiB  [8192][1024]  (total 88 MiB)

  cvt_kernel<<<4096, 256, 0, stream>>>(x,  xb);
  cvt_kernel<<<1536, 256, 0, stream>>>(Wa, wab);
  cvt_kernel<<< 512, 256, 0, stream>>>(Wp, wpb);

  gemm_bt<0><<<dim3(24, 64), 256, 0, stream>>>(xb, wab, ba, 8192, 3072, 1024,
                                               qws, kws, vT, nullptr);
  attn_kernel<<<dim3(32, 64), 256, 0, stream>>>(qws, kws, vT, yws);
  gemm_bt<1><<<dim3(8, 64), 256, 0, stream>>>(yws, wpb, bp, 8192, 1024, 1024,
                                              nullptr, nullptr, nullptr, out);
}